// Round 6
// baseline (226.961 us; speedup 1.0000x reference)
//
#include <hip/hip_runtime.h>

// Problem constants: x [L,B,E], H heads, head dim 64.
#define L_DIM 1024
#define B_DIM 8
#define E_DIM 1024
#define H_DIM 16
#define HD 64
#define BH_DIM (B_DIM * H_DIM)  // 128

typedef float f32x4 __attribute__((ext_vector_type(4)));
typedef _Float16 f16_t;
typedef f16_t f16x4 __attribute__((ext_vector_type(4)));
typedef f16_t f16x8 __attribute__((ext_vector_type(8)));

// async global->LDS, 16 B per lane (m97 pattern): wave-uniform base + lane*16.
static __device__ __forceinline__ void gld16(const void* g, void* l) {
  __builtin_amdgcn_global_load_lds(
      (const __attribute__((address_space(1))) unsigned int*)g,
      (__attribute__((address_space(3))) unsigned int*)l, 16, 0, 0);
}

// fp32 -> f16 pre-convert of x, w_in, w_out (grid-stride over float4 units).
__global__ __launch_bounds__(256) void convert_f16(
    const float* __restrict__ x, const float* __restrict__ wi,
    const float* __restrict__ wo, f16_t* __restrict__ x16,
    f16_t* __restrict__ wi16, f16_t* __restrict__ wo16) {
  const int NX = (L_DIM * B_DIM * E_DIM) / 4;   // 2097152
  const int NWI = (3 * E_DIM * E_DIM) / 4;      // 786432
  const int NWO = (E_DIM * E_DIM) / 4;          // 262144
  const int total = NX + NWI + NWO;
  for (int i = blockIdx.x * blockDim.x + threadIdx.x; i < total;
       i += gridDim.x * blockDim.x) {
    const float4* src; f16_t* dst; int j;
    if (i < NX)            { src = (const float4*)x;  dst = x16;  j = i; }
    else if (i < NX + NWI) { src = (const float4*)wi; dst = wi16; j = i - NX; }
    else                   { src = (const float4*)wo; dst = wo16; j = i - NX - NWI; }
    const float4 v = src[j];
    f16x4 h = {(f16_t)v.x, (f16_t)v.y, (f16_t)v.z, (f16_t)v.w};
    *(f16x4*)(dst + (size_t)j * 4) = h;
  }
}

// ---------------------------------------------------------------------------
// QKV GEMM (round-5 structure, UNCHANGED: empirical plateau ~678 TF, 76 us).
// 128x128 tile, BK=64, dbuf 64 KiB LDS, 2 blocks/CU, grid 1536 = 3x512 exact.
// ---------------------------------------------------------------------------

#define GQ_FENCE asm volatile("" ::: "memory")
#define GQ_BARRIER do { GQ_FENCE; __builtin_amdgcn_s_barrier(); GQ_FENCE; } while (0)
#define VMW(n) asm volatile("s_waitcnt vmcnt(" #n ")" ::: "memory")

// swizzled frag pointer: logical byte = r*128 + ks*64 + quad*16, physical
// XORs (r&7)<<4.  r always = base + l16 so r&7 == l16&7.
static __device__ __forceinline__ const f16x8* fp16frag(
    const f16_t* tile, int r, int ks, int quad, int l16) {
  const int bo = (r * 128 + ks * 64 + quad * 16) ^ ((l16 & 7) << 4);
  return (const f16x8*)((const char*)tile + bo);
}

__global__ __launch_bounds__(256, 2) void gemm_qkv(
    const f16_t* __restrict__ A, const f16_t* __restrict__ B,
    const float* __restrict__ bias, f16_t* __restrict__ Oq,
    f16_t* __restrict__ Ok, f16_t* __restrict__ Ov) {
  constexpr int K = 1024;
  __shared__ __align__(16) f16_t As[2 * 8192];  // 32 KB: dbuf x 128x64
  __shared__ __align__(16) f16_t Bs[2 * 8192];  // 32 KB

  const int tid = threadIdx.x;
  const int lane = tid & 63;
  const int w = tid >> 6;        // 0..3
  const int wm = (w & 1) * 64;
  const int wn = (w >> 1) * 64;
  const int quad = lane >> 4;
  const int l16 = lane & 15;

  // XCD swizzle: 1536 wg = 8 XCDs x 192.
  const int bid = blockIdx.x;
  const int xcd = bid & 7;
  const int idx = bid >> 3;            // 0..191
  const int tm = xcd * 8 + (idx & 7);  // 0..63
  const int tn = idx >> 3;             // 0..23
  const int m0 = tm * 128;
  const int n0 = tn * 128;

  const int r8 = tid >> 3;                    // 0..31
  const int gsw = (tid & 7) ^ (r8 & 7);
  const f16_t* Abase = A + (size_t)(m0 + r8) * K + gsw * 8;
  const f16_t* Bbase = B + (size_t)(n0 + r8) * K + gsw * 8;

#define STAGE(kt, d) do {                                                    \
    _Pragma("unroll") for (int s_ = 0; s_ < 4; ++s_)                         \
      gld16(Abase + (size_t)s_ * 32 * K + (kt) * 64,                         \
            &As[(d) * 8192 + s_ * 2048 + tid * 8]);                          \
    _Pragma("unroll") for (int s_ = 0; s_ < 4; ++s_)                         \
      gld16(Bbase + (size_t)s_ * 32 * K + (kt) * 64,                         \
            &Bs[(d) * 8192 + s_ * 2048 + tid * 8]);                          \
  } while (0)

  f32x4 acc[4][4] = {};

  STAGE(0, 0);
  STAGE(1, 1);

#pragma unroll
  for (int t = 0; t < 16; ++t) {
    const int d = t & 1;
    VMW(8);
    GQ_BARRIER;

    f16x8 af[4][2], bf[4][2];
#pragma unroll
    for (int i = 0; i < 4; ++i)
#pragma unroll
      for (int ks = 0; ks < 2; ++ks) {
        af[i][ks] = *fp16frag(&As[d * 8192], wm + i * 16 + l16, ks, quad, l16);
        bf[i][ks] = *fp16frag(&Bs[d * 8192], wn + i * 16 + l16, ks, quad, l16);
      }

    __builtin_amdgcn_s_setprio(1);
#pragma unroll
    for (int i = 0; i < 4; ++i)
#pragma unroll
      for (int j = 0; j < 4; ++j)
#pragma unroll
        for (int ks = 0; ks < 2; ++ks)
          acc[i][j] = __builtin_amdgcn_mfma_f32_16x16x32_f16(
              af[i][ks], bf[j][ks], acc[i][j], 0, 0, 0);
    __builtin_amdgcn_s_setprio(0);

    GQ_BARRIER;
    const int kt2 = (t + 2 < 16) ? t + 2 : 15;
    STAGE(kt2, d);
  }

#pragma unroll
  for (int i = 0; i < 4; ++i) {
    const int mbase = m0 + wm + i * 16 + quad * 4;
#pragma unroll
    for (int c = 0; c < 4; ++c) {
      const int n = n0 + wn + c * 16 + l16;
      const float bv = bias[n];
      const int chunk = n >> 10;      // 0=q 1=k 2=v
      const int e = n & 1023;
      const int h = e >> 6;
      const int dd = e & 63;
#pragma unroll
      for (int r = 0; r < 4; ++r) {
        const int m = mbase + r;
        const int l = m >> 3, b = m & 7;          // row m = l*B + b
        const size_t idxo = ((size_t)(b * H_DIM + h) * L_DIM + l) * HD + dd;
        const float val = acc[i][c][r] + bv;
        if (chunk == 0)      Oq[idxo] = (f16_t)(val * 0.125f);  // 64^-0.5
        else if (chunk == 1) Ok[idxo] = (f16_t)val;
        else                 Ov[idxo] = (f16_t)val;
      }
    }
  }
#undef STAGE
}

// ---------------------------------------------------------------------------
// Out-proj GEMM kept on the m97 128x128 structure (unchanged for isolation).
// ---------------------------------------------------------------------------
template <int MODE>
__global__ __launch_bounds__(256, 2) void gemm_f16(
    const f16_t* __restrict__ A, const f16_t* __restrict__ B,
    const float* __restrict__ bias, void* __restrict__ O0v,
    void* __restrict__ O1v, void* __restrict__ O2v) {
  constexpr int K = 1024;
  __shared__ __align__(16) f16_t As[128 * 32];
  __shared__ __align__(16) f16_t Bs[128 * 32];

  const int tid = threadIdx.x;
  const int lane = tid & 63;
  const int wave = tid >> 6;
  const int wm = (wave & 1) * 64;
  const int wn = (wave >> 1) * 64;
  const int quad = lane >> 4;
  const int l16 = lane & 15;
  const int m0 = blockIdx.y * 128;
  const int n0 = blockIdx.x * 128;

  const int cr = tid >> 2;
  const int cc = (tid & 3) * 8;

  f32x4 acc[4][4] = {};

  for (int k0 = 0; k0 < K; k0 += 32) {
    __syncthreads();
    gld16(A + (size_t)(m0 + cr) * K + k0 + cc,      As + tid * 8);
    gld16(A + (size_t)(m0 + 64 + cr) * K + k0 + cc, As + 2048 + tid * 8);
    gld16(B + (size_t)(n0 + cr) * K + k0 + cc,      Bs + tid * 8);
    gld16(B + (size_t)(n0 + 64 + cr) * K + k0 + cc, Bs + 2048 + tid * 8);
    __syncthreads();

    f16x8 af[4], bfr[4];
#pragma unroll
    for (int t = 0; t < 4; ++t) {
      af[t]  = *(const f16x8*)&As[(wm + t * 16 + l16) * 32 + quad * 8];
      bfr[t] = *(const f16x8*)&Bs[(wn + t * 16 + l16) * 32 + quad * 8];
    }
#pragma unroll
    for (int i = 0; i < 4; ++i)
#pragma unroll
      for (int j = 0; j < 4; ++j)
        acc[i][j] = __builtin_amdgcn_mfma_f32_16x16x32_f16(af[i], bfr[j], acc[i][j], 0, 0, 0);
  }

#pragma unroll
  for (int i = 0; i < 4; ++i) {
    const int mbase = m0 + wm + i * 16 + quad * 4;
#pragma unroll
    for (int j = 0; j < 4; ++j) {
      const int n = n0 + wn + j * 16 + l16;
      const float bv = bias[n];
      if (MODE == 0) {
        f16_t* O0 = (f16_t*)O0v; f16_t* O1 = (f16_t*)O1v; f16_t* O2 = (f16_t*)O2v;
        const int chunk = n >> 10;
        const int e = n & 1023;
        const int h = e >> 6;
        const int d = e & 63;
#pragma unroll
        for (int r = 0; r < 4; ++r) {
          const int m = mbase + r;
          const int l = m >> 3, b = m & 7;
          const size_t idx = ((size_t)(b * H_DIM + h) * L_DIM + l) * HD + d;
          const float val = acc[i][j][r] + bv;
          if (chunk == 0)      O0[idx] = (f16_t)(val * 0.125f);
          else if (chunk == 1) O1[idx] = (f16_t)val;
          else                 O2[idx] = (f16_t)val;
        }
      } else {
        float* O0 = (float*)O0v;
#pragma unroll
        for (int r = 0; r < 4; ++r) {
          const int m = mbase + r;
          O0[(size_t)m * E_DIM + n] = acc[i][j][r] + bv;
        }
      }
    }
  }
}

// ---------------------------------------------------------------------------
// Attention v6: round-6 change — double-buffered K/V LDS + T14 async-stage
// split + one RAW barrier per kt (no vmcnt drain at barriers).
//
// v5 paid full global-load latency inside a __syncthreads() pair EVERY kt
// (~600-900 cyc x 16), plus 2 barriers with implicit vmcnt(0) drains.  v6:
//   per kt: COMPUTE(buf cur)                       (MFMA+exp, setprio'd)
//           WRITEKV(buf nxt)  <- regs loaded one full compute earlier
//           LOADKV(kt+2) -> regs                   (in flight across barrier)
//           lgkmcnt(0); s_barrier                  (publish ds_writes ONLY)
// WAR safety: writes target the buffer last read in compute(kt-1); every
// wave finished those reads before the barrier that ended kt-1.
// Math, layouts (KSTR=70 pad, permuted key->row), epilogue: unchanged.
// ---------------------------------------------------------------------------
__global__ __launch_bounds__(256, 2) void attn_f16(
    const f16_t* __restrict__ Q, const f16_t* __restrict__ K,
    const f16_t* __restrict__ V, f16_t* __restrict__ O) {
  constexpr int KSTR = 70;  // odd-dword row stride: <=2-way banks on frag reads
  __shared__ __align__(16) f16_t Ks[2][64 * KSTR];   // [key][d]
  __shared__ __align__(16) f16_t Vs[2][64 * KSTR];   // [d][key]  (V^T)
  __shared__ float Ls[4][64];

  const int tid = threadIdx.x;
  const int lane = tid & 63;
  const int w = tid >> 6;
  const int quad = lane >> 4;
  const int l16 = lane & 15;
  const int bh = blockIdx.y;
  const int q0 = blockIdx.x * 256 + w * 64;

  const f16_t* Qb = Q + (size_t)bh * L_DIM * HD;
  const f16_t* Kb = K + (size_t)bh * L_DIM * HD;
  const f16_t* Vb = V + (size_t)bh * L_DIM * HD;  // [key][d]

  // Q as B-operand frags (n=q=l16, k=d=quad*8+j).
  f16x8 qf[4][2];
#pragma unroll
  for (int nt = 0; nt < 4; ++nt)
#pragma unroll
    for (int kc = 0; kc < 2; ++kc)
      qf[nt][kc] = *(const f16x8*)(Qb + (size_t)(q0 + nt * 16 + l16) * HD + kc * 32 + quad * 8);

  f32x4 oacc[4][4] = {};   // [q-tile][d-tile]
  float rsum[4] = {0.0f, 0.0f, 0.0f, 0.0f};

  const int sr = tid >> 3;        // K staging row 0..31
  const int sc8 = (tid & 7) * 8;  // K staging col
  const int va = tid & 31;        // V staging: d-pair index
  const int vg = tid >> 5;        // V staging: key-group 0..7
  const int rA = (l16 >> 2) * 8 + (l16 & 3);  // permuted A-row base

  // staging registers (one set, refilled after each write)
  f16x8 kreg[2];
  unsigned int vd[8];

#define LOADKV(kt) do {                                                      \
    _Pragma("unroll") for (int rr_ = 0; rr_ < 2; ++rr_)                      \
      kreg[rr_] = *(const f16x8*)(Kb +                                       \
          (size_t)((kt) * 64 + sr + rr_ * 32) * HD + sc8);                   \
    const f16_t* vp_ = Vb + (size_t)((kt) * 64 + vg * 8) * HD + 2 * va;      \
    _Pragma("unroll") for (int i_ = 0; i_ < 8; ++i_)                         \
      vd[i_] = *(const unsigned int*)(vp_ + (size_t)i_ * HD);                \
  } while (0)

#define WRITEKV(nb) do {                                                     \
    _Pragma("unroll") for (int rr_ = 0; rr_ < 2; ++rr_)                      \
      *(f16x8*)&Ks[nb][(sr + rr_ * 32) * KSTR + sc8] = kreg[rr_];            \
    union { unsigned int u[4]; f16x8 v; } lo_, hi_;                          \
    _Pragma("unroll") for (int i_ = 0; i_ < 4; ++i_) {                       \
      lo_.u[i_] = (vd[2 * i_] & 0xffffu) | (vd[2 * i_ + 1] << 16);           \
      hi_.u[i_] = (vd[2 * i_] >> 16) | (vd[2 * i_ + 1] & 0xffff0000u);       \
    }                                                                        \
    *(f16x8*)&Vs[nb][(2 * va) * KSTR + vg * 8] = lo_.v;                      \
    *(f16x8*)&Vs[nb][(2 * va + 1) * KSTR + vg * 8] = hi_.v;                  \
  } while (0)

// publish ds_writes across waves WITHOUT draining vmcnt (in-flight global
// loads cross the barrier -- that's the whole point).
#define ATTN_SYNC do {                                                       \
    GQ_FENCE;                                                                \
    asm volatile("s_waitcnt lgkmcnt(0)" ::: "memory");                       \
    __builtin_amdgcn_s_barrier();                                            \
    GQ_FENCE;                                                                \
  } while (0)

#define ATTN_COMPUTE(nb) do {                                                \
    _Pragma("unroll") for (int c = 0; c < 2; ++c) {                          \
      f32x4 scv[2][4] = {};                                                  \
      __builtin_amdgcn_s_setprio(1);                                         \
      _Pragma("unroll") for (int h = 0; h < 2; ++h) {                        \
        const int row = c * 32 + h * 4 + rA;                                 \
        _Pragma("unroll") for (int kc = 0; kc < 2; ++kc) {                   \
          const f16x8 ka = *(const f16x8*)&Ks[nb][row * KSTR + kc * 32 + quad * 8]; \
          _Pragma("unroll") for (int nt = 0; nt < 4; ++nt)                   \
            scv[h][nt] = __builtin_amdgcn_mfma_f32_16x16x32_f16(             \
                ka, qf[nt][kc], scv[h][nt], 0, 0, 0);                        \
        }                                                                    \
      }                                                                      \
      __builtin_amdgcn_s_setprio(0);                                         \
      f16x8 pa[4];                                                           \
      _Pragma("unroll") for (int nt = 0; nt < 4; ++nt)                       \
        _Pragma("unroll") for (int h = 0; h < 2; ++h)                        \
          _Pragma("unroll") for (int r = 0; r < 4; ++r) {                    \
            const float e = __expf(scv[h][nt][r]);                           \
            rsum[nt] += e;                                                   \
            pa[nt][h * 4 + r] = (f16_t)e;                                    \
          }                                                                  \
      __builtin_amdgcn_s_setprio(1);                                         \
      _Pragma("unroll") for (int nd = 0; nd < 4; ++nd) {                     \
        const f16x8 vb = *(const f16x8*)&Vs[nb][(nd * 16 + l16) * KSTR + c * 32 + quad * 8]; \
        _Pragma("unroll") for (int nt = 0; nt < 4; ++nt)                     \
          oacc[nt][nd] = __builtin_amdgcn_mfma_f32_16x16x32_f16(             \
              pa[nt], vb, oacc[nt][nd], 0, 0, 0);                            \
      }                                                                      \
      __builtin_amdgcn_s_setprio(0);                                         \
    }                                                                        \
  } while (0)

  // Prologue: tile 0 staged (write latency exposed once), tile 1 in flight.
  LOADKV(0);
  WRITEKV(0);
  LOADKV(1);
  ATTN_SYNC;

  // Steady state: kt = 0..13 in even/odd pairs (compile-time buffer index).
  for (int kt = 0; kt < 14; kt += 2) {
    ATTN_COMPUTE(0);
    WRITEKV(1);          // regs = tile kt+1 (issued one compute ago)
    LOADKV(kt + 2);
    ATTN_SYNC;
    ATTN_COMPUTE(1);
    WRITEKV(0);          // regs = tile kt+2
    LOADKV(kt + 3);
    ATTN_SYNC;
  }
  // kt = 14: compute buf0, stage tile 15 (regs already loaded), no new loads.
  ATTN_COMPUTE(0);
  WRITEKV(1);
  ATTN_SYNC;
  // kt = 15
  ATTN_COMPUTE(1);

#undef LOADKV
#undef WRITEKV
#undef ATTN_SYNC
#undef ATTN_COMPUTE

  // Denominators: keys partitioned across quads -> reduce over quads.
#pragma unroll
  for (int nt = 0; nt < 4; ++nt) {
    float rs = rsum[nt];
    rs += __shfl_xor(rs, 16); rs += __shfl_xor(rs, 32);
    if (quad == 0) Ls[w][nt * 16 + l16] = rs;
  }
  asm volatile("s_waitcnt lgkmcnt(0)" ::: "memory");  // wave-private RAW

  // Epilogue: ao16[l, b, h*64+d] = oacc / denom (f16, feeds out-proj GEMM).
  const int b = bh >> 4;
  const int h = bh & 15;
#pragma unroll
  for (int nt = 0; nt < 4; ++nt)
#pragma unroll
    for (int r = 0; r < 4; ++r) {
      const int ql = nt * 16 + quad * 4 + r;
      const float inv = 1.0f / Ls[w][ql];
      const int qrow = q0 + ql;
#pragma unroll
      for (int nd = 0; nd < 4; ++nd) {
        const int d = nd * 16 + l16;
        O[((size_t)qrow * B_DIM + b) * E_DIM + h * HD + d] = (f16_t)(oacc[nt][nd][r] * inv);
      }
    }
}

extern "C" void kernel_launch(void* const* d_in, const int* in_sizes, int n_in,
                              void* d_out, int out_size, void* d_ws, size_t ws_size,
                              hipStream_t stream) {
  const float* x     = (const float*)d_in[0];
  const float* w_in  = (const float*)d_in[1];
  const float* b_in  = (const float*)d_in[2];
  const float* w_out = (const float*)d_in[3];
  const float* b_out = (const float*)d_in[4];

  const size_t TS = (size_t)BH_DIM * L_DIM * HD;  // 8M elements per tensor
  f16_t* q16  = (f16_t*)d_ws;
  f16_t* k16  = q16 + TS;
  f16_t* v16  = k16 + TS;
  f16_t* x16  = v16 + TS;
  f16_t* wi16 = x16 + TS;
  f16_t* wo16 = wi16 + (size_t)3 * E_DIM * E_DIM;
  f16_t* ao16 = x16;   // alias: x16 dead after QKV GEMM

  // 0) fp32 -> f16 pre-convert (x, w_in, w_out)
  convert_f16<<<4096, 256, 0, stream>>>(x, w_in, w_out, x16, wi16, wo16);
  // 1) QKV projection: 128^2 dbuf BK=64, 2 blocks/CU, grid 1536 (3x512 exact)
  gemm_qkv<<<1536, 256, 0, stream>>>(x16, wi16, b_in, q16, k16, v16);
  // 2) attention v6: dbuf K/V + async-stage split, 1 barrier/kt
  attn_f16<<<dim3(4, 128), 256, 0, stream>>>(q16, k16, v16, ao16);
  // 3) out projection: [8192,1024] x [1024,1024]^T -> fp32 d_out
  gemm_f16<1><<<dim3(8, 64), 256, 0, stream>>>(ao16, wo16, b_out, d_out, nullptr, nullptr);
}

// Round 9
// 225.197 us; speedup vs baseline: 1.0078x; 1.0078x over previous
//
#include <hip/hip_runtime.h>

// Problem constants: x [L,B,E], H heads, head dim 64.
#define L_DIM 1024
#define B_DIM 8
#define E_DIM 1024
#define H_DIM 16
#define HD 64
#define BH_DIM (B_DIM * H_DIM)  // 128

typedef float f32x4 __attribute__((ext_vector_type(4)));
typedef _Float16 f16_t;
typedef f16_t f16x4 __attribute__((ext_vector_type(4)));
typedef f16_t f16x8 __attribute__((ext_vector_type(8)));

// async global->LDS, 16 B per lane (m97 pattern): wave-uniform base + lane*16.
static __device__ __forceinline__ void gld16(const void* g, void* l) {
  __builtin_amdgcn_global_load_lds(
      (const __attribute__((address_space(1))) unsigned int*)g,
      (__attribute__((address_space(3))) unsigned int*)l, 16, 0, 0);
}

// fp32 -> f16 pre-convert of x, w_in, w_out (grid-stride over float4 units).
__global__ __launch_bounds__(256) void convert_f16(
    const float* __restrict__ x, const float* __restrict__ wi,
    const float* __restrict__ wo, f16_t* __restrict__ x16,
    f16_t* __restrict__ wi16, f16_t* __restrict__ wo16) {
  const int NX = (L_DIM * B_DIM * E_DIM) / 4;   // 2097152
  const int NWI = (3 * E_DIM * E_DIM) / 4;      // 786432
  const int NWO = (E_DIM * E_DIM) / 4;          // 262144
  const int total = NX + NWI + NWO;
  for (int i = blockIdx.x * blockDim.x + threadIdx.x; i < total;
       i += gridDim.x * blockDim.x) {
    const float4* src; f16_t* dst; int j;
    if (i < NX)            { src = (const float4*)x;  dst = x16;  j = i; }
    else if (i < NX + NWI) { src = (const float4*)wi; dst = wi16; j = i - NX; }
    else                   { src = (const float4*)wo; dst = wo16; j = i - NX - NWI; }
    const float4 v = src[j];
    f16x4 h = {(f16_t)v.x, (f16_t)v.y, (f16_t)v.z, (f16_t)v.w};
    *(f16x4*)(dst + (size_t)j * 4) = h;
  }
}

// ---------------------------------------------------------------------------
// QKV GEMM (round-5 structure, UNCHANGED — measured 61 us / 845 TF /
// MfmaUtil 35% in round 6).  128x128 tile, BK=64, dbuf 64 KiB LDS,
// 2 blocks/CU, grid 1536 = 3x512 exact, counted vmcnt(8), XOR swizzle.
// ---------------------------------------------------------------------------

#define GQ_FENCE asm volatile("" ::: "memory")
#define GQ_BARRIER do { GQ_FENCE; __builtin_amdgcn_s_barrier(); GQ_FENCE; } while (0)
#define VMW(n) asm volatile("s_waitcnt vmcnt(" #n ")" ::: "memory")

// swizzled frag pointer: logical byte = r*128 + ks*64 + quad*16, physical
// XORs (r&7)<<4.  r always = base + l16 so r&7 == l16&7.
static __device__ __forceinline__ const f16x8* fp16frag(
    const f16_t* tile, int r, int ks, int quad, int l16) {
  const int bo = (r * 128 + ks * 64 + quad * 16) ^ ((l16 & 7) << 4);
  return (const f16x8*)((const char*)tile + bo);
}

__global__ __launch_bounds__(256, 2) void gemm_qkv(
    const f16_t* __restrict__ A, const f16_t* __restrict__ B,
    const float* __restrict__ bias, f16_t* __restrict__ Oq,
    f16_t* __restrict__ Ok, f16_t* __restrict__ Ov) {
  constexpr int K = 1024;
  __shared__ __align__(16) f16_t As[2 * 8192];  // 32 KB: dbuf x 128x64
  __shared__ __align__(16) f16_t Bs[2 * 8192];  // 32 KB

  const int tid = threadIdx.x;
  const int lane = tid & 63;
  const int w = tid >> 6;        // 0..3
  const int wm = (w & 1) * 64;
  const int wn = (w >> 1) * 64;
  const int quad = lane >> 4;
  const int l16 = lane & 15;

  // XCD swizzle: 1536 wg = 8 XCDs x 192.
  const int bid = blockIdx.x;
  const int xcd = bid & 7;
  const int idx = bid >> 3;            // 0..191
  const int tm = xcd * 8 + (idx & 7);  // 0..63
  const int tn = idx >> 3;             // 0..23
  const int m0 = tm * 128;
  const int n0 = tn * 128;

  const int r8 = tid >> 3;                    // 0..31
  const int gsw = (tid & 7) ^ (r8 & 7);
  const f16_t* Abase = A + (size_t)(m0 + r8) * K + gsw * 8;
  const f16_t* Bbase = B + (size_t)(n0 + r8) * K + gsw * 8;

#define STAGE(kt, d) do {                                                    \
    _Pragma("unroll") for (int s_ = 0; s_ < 4; ++s_)                         \
      gld16(Abase + (size_t)s_ * 32 * K + (kt) * 64,                         \
            &As[(d) * 8192 + s_ * 2048 + tid * 8]);                          \
    _Pragma("unroll") for (int s_ = 0; s_ < 4; ++s_)                         \
      gld16(Bbase + (size_t)s_ * 32 * K + (kt) * 64,                         \
            &Bs[(d) * 8192 + s_ * 2048 + tid * 8]);                          \
  } while (0)

  f32x4 acc[4][4] = {};

  STAGE(0, 0);
  STAGE(1, 1);

#pragma unroll
  for (int t = 0; t < 16; ++t) {
    const int d = t & 1;
    VMW(8);
    GQ_BARRIER;

    f16x8 af[4][2], bf[4][2];
#pragma unroll
    for (int i = 0; i < 4; ++i)
#pragma unroll
      for (int ks = 0; ks < 2; ++ks) {
        af[i][ks] = *fp16frag(&As[d * 8192], wm + i * 16 + l16, ks, quad, l16);
        bf[i][ks] = *fp16frag(&Bs[d * 8192], wn + i * 16 + l16, ks, quad, l16);
      }

    __builtin_amdgcn_s_setprio(1);
#pragma unroll
    for (int i = 0; i < 4; ++i)
#pragma unroll
      for (int j = 0; j < 4; ++j)
#pragma unroll
        for (int ks = 0; ks < 2; ++ks)
          acc[i][j] = __builtin_amdgcn_mfma_f32_16x16x32_f16(
              af[i][ks], bf[j][ks], acc[i][j], 0, 0, 0);
    __builtin_amdgcn_s_setprio(0);

    GQ_BARRIER;
    const int kt2 = (t + 2 < 16) ? t + 2 : 15;
    STAGE(kt2, d);
  }

#pragma unroll
  for (int i = 0; i < 4; ++i) {
    const int mbase = m0 + wm + i * 16 + quad * 4;
#pragma unroll
    for (int c = 0; c < 4; ++c) {
      const int n = n0 + wn + c * 16 + l16;
      const float bv = bias[n];
      const int chunk = n >> 10;      // 0=q 1=k 2=v
      const int e = n & 1023;
      const int h = e >> 6;
      const int dd = e & 63;
#pragma unroll
      for (int r = 0; r < 4; ++r) {
        const int m = mbase + r;
        const int l = m >> 3, b = m & 7;          // row m = l*B + b
        const size_t idxo = ((size_t)(b * H_DIM + h) * L_DIM + l) * HD + dd;
        const float val = acc[i][c][r] + bv;
        if (chunk == 0)      Oq[idxo] = (f16_t)(val * 0.125f);  // 64^-0.5
        else if (chunk == 1) Ok[idxo] = (f16_t)val;
        else                 Ov[idxo] = (f16_t)val;
      }
    }
  }
#undef STAGE
}

// ---------------------------------------------------------------------------
// Out-proj GEMM, round-7: ported to the round-5 dbuf template (was m97
// 2-barrier, ~27% MfmaUtil).  C[8192,1024] = A[8192,1024] x B[1024,1024]^T
// + bias -> fp32.  Grid 512 = 64x8 tiles = EXACTLY 2 blocks/CU, one round.
// Same counted-vmcnt(8) 2-deep prefetch, XOR swizzle, setprio.
// XCD swizzle: 512 = 8 XCDs x 64; per XCD tm in [8x,8x+8) (A slab 2 MB,
// L2-resident), tn sweeps 0..7 (B slab 0.25 MB per tn).
// ---------------------------------------------------------------------------
__global__ __launch_bounds__(256, 2) void gemm_out(
    const f16_t* __restrict__ A, const f16_t* __restrict__ B,
    const float* __restrict__ bias, float* __restrict__ O) {
  constexpr int K = 1024;
  __shared__ __align__(16) f16_t As[2 * 8192];  // 32 KB
  __shared__ __align__(16) f16_t Bs[2 * 8192];  // 32 KB

  const int tid = threadIdx.x;
  const int lane = tid & 63;
  const int w = tid >> 6;        // 0..3
  const int wm = (w & 1) * 64;
  const int wn = (w >> 1) * 64;
  const int quad = lane >> 4;
  const int l16 = lane & 15;

  const int bid = blockIdx.x;
  const int xcd = bid & 7;
  const int idx = bid >> 3;            // 0..63
  const int tm = xcd * 8 + (idx & 7);  // 0..63
  const int tn = idx >> 3;             // 0..7
  const int m0 = tm * 128;
  const int n0 = tn * 128;

  const int r8 = tid >> 3;                    // 0..31
  const int gsw = (tid & 7) ^ (r8 & 7);
  const f16_t* Abase = A + (size_t)(m0 + r8) * K + gsw * 8;
  const f16_t* Bbase = B + (size_t)(n0 + r8) * K + gsw * 8;

#define STAGE(kt, d) do {                                                    \
    _Pragma("unroll") for (int s_ = 0; s_ < 4; ++s_)                         \
      gld16(Abase + (size_t)s_ * 32 * K + (kt) * 64,                         \
            &As[(d) * 8192 + s_ * 2048 + tid * 8]);                          \
    _Pragma("unroll") for (int s_ = 0; s_ < 4; ++s_)                         \
      gld16(Bbase + (size_t)s_ * 32 * K + (kt) * 64,                         \
            &Bs[(d) * 8192 + s_ * 2048 + tid * 8]);                          \
  } while (0)

  f32x4 acc[4][4] = {};

  STAGE(0, 0);
  STAGE(1, 1);

#pragma unroll
  for (int t = 0; t < 16; ++t) {
    const int d = t & 1;
    VMW(8);
    GQ_BARRIER;

    f16x8 af[4][2], bf[4][2];
#pragma unroll
    for (int i = 0; i < 4; ++i)
#pragma unroll
      for (int ks = 0; ks < 2; ++ks) {
        af[i][ks] = *fp16frag(&As[d * 8192], wm + i * 16 + l16, ks, quad, l16);
        bf[i][ks] = *fp16frag(&Bs[d * 8192], wn + i * 16 + l16, ks, quad, l16);
      }

    __builtin_amdgcn_s_setprio(1);
#pragma unroll
    for (int i = 0; i < 4; ++i)
#pragma unroll
      for (int j = 0; j < 4; ++j)
#pragma unroll
        for (int ks = 0; ks < 2; ++ks)
          acc[i][j] = __builtin_amdgcn_mfma_f32_16x16x32_f16(
              af[i][ks], bf[j][ks], acc[i][j], 0, 0, 0);
    __builtin_amdgcn_s_setprio(0);

    GQ_BARRIER;
    const int kt2 = (t + 2 < 16) ? t + 2 : 15;
    STAGE(kt2, d);
  }

  // fp32 epilogue with bias; C/D layout col=l16, row=quad*4+r.
#pragma unroll
  for (int i = 0; i < 4; ++i) {
    const int mbase = m0 + wm + i * 16 + quad * 4;
#pragma unroll
    for (int c = 0; c < 4; ++c) {
      const int n = n0 + wn + c * 16 + l16;
      const float bv = bias[n];
#pragma unroll
      for (int r = 0; r < 4; ++r) {
        const int m = mbase + r;
        O[(size_t)m * E_DIM + n] = acc[i][c][r] + bv;
      }
    }
  }
#undef STAGE
}

// ---------------------------------------------------------------------------
// Attention v6 (round-6 structure, UNCHANGED): dbuf K/V LDS + async-stage
// split (T14), one RAW barrier per kt, no vmcnt drain at barriers.
// ---------------------------------------------------------------------------
__global__ __launch_bounds__(256, 2) void attn_f16(
    const f16_t* __restrict__ Q, const f16_t* __restrict__ K,
    const f16_t* __restrict__ V, f16_t* __restrict__ O) {
  constexpr int KSTR = 70;  // odd-dword row stride: <=2-way banks on frag reads
  __shared__ __align__(16) f16_t Ks[2][64 * KSTR];   // [key][d]
  __shared__ __align__(16) f16_t Vs[2][64 * KSTR];   // [d][key]  (V^T)
  __shared__ float Ls[4][64];

  const int tid = threadIdx.x;
  const int lane = tid & 63;
  const int w = tid >> 6;
  const int quad = lane >> 4;
  const int l16 = lane & 15;
  const int bh = blockIdx.y;
  const int q0 = blockIdx.x * 256 + w * 64;

  const f16_t* Qb = Q + (size_t)bh * L_DIM * HD;
  const f16_t* Kb = K + (size_t)bh * L_DIM * HD;
  const f16_t* Vb = V + (size_t)bh * L_DIM * HD;  // [key][d]

  // Q as B-operand frags (n=q=l16, k=d=quad*8+j).
  f16x8 qf[4][2];
#pragma unroll
  for (int nt = 0; nt < 4; ++nt)
#pragma unroll
    for (int kc = 0; kc < 2; ++kc)
      qf[nt][kc] = *(const f16x8*)(Qb + (size_t)(q0 + nt * 16 + l16) * HD + kc * 32 + quad * 8);

  f32x4 oacc[4][4] = {};   // [q-tile][d-tile]
  float rsum[4] = {0.0f, 0.0f, 0.0f, 0.0f};

  const int sr = tid >> 3;        // K staging row 0..31
  const int sc8 = (tid & 7) * 8;  // K staging col
  const int va = tid & 31;        // V staging: d-pair index
  const int vg = tid >> 5;        // V staging: key-group 0..7
  const int rA = (l16 >> 2) * 8 + (l16 & 3);  // permuted A-row base

  // staging registers (one set, refilled after each write)
  f16x8 kreg[2];
  unsigned int vd[8];

#define LOADKV(kt) do {                                                      \
    _Pragma("unroll") for (int rr_ = 0; rr_ < 2; ++rr_)                      \
      kreg[rr_] = *(const f16x8*)(Kb +                                       \
          (size_t)((kt) * 64 + sr + rr_ * 32) * HD + sc8);                   \
    const f16_t* vp_ = Vb + (size_t)((kt) * 64 + vg * 8) * HD + 2 * va;      \
    _Pragma("unroll") for (int i_ = 0; i_ < 8; ++i_)                         \
      vd[i_] = *(const unsigned int*)(vp_ + (size_t)i_ * HD);                \
  } while (0)

#define WRITEKV(nb) do {                                                     \
    _Pragma("unroll") for (int rr_ = 0; rr_ < 2; ++rr_)                      \
      *(f16x8*)&Ks[nb][(sr + rr_ * 32) * KSTR + sc8] = kreg[rr_];            \
    union { unsigned int u[4]; f16x8 v; } lo_, hi_;                          \
    _Pragma("unroll") for (int i_ = 0; i_ < 4; ++i_) {                       \
      lo_.u[i_] = (vd[2 * i_] & 0xffffu) | (vd[2 * i_ + 1] << 16);           \
      hi_.u[i_] = (vd[2 * i_] >> 16) | (vd[2 * i_ + 1] & 0xffff0000u);       \
    }                                                                        \
    *(f16x8*)&Vs[nb][(2 * va) * KSTR + vg * 8] = lo_.v;                      \
    *(f16x8*)&Vs[nb][(2 * va + 1) * KSTR + vg * 8] = hi_.v;                  \
  } while (0)

#define ATTN_SYNC do {                                                       \
    GQ_FENCE;                                                                \
    asm volatile("s_waitcnt lgkmcnt(0)" ::: "memory");                       \
    __builtin_amdgcn_s_barrier();                                            \
    GQ_FENCE;                                                                \
  } while (0)

#define ATTN_COMPUTE(nb) do {                                                \
    _Pragma("unroll") for (int c = 0; c < 2; ++c) {                          \
      f32x4 scv[2][4] = {};                                                  \
      __builtin_amdgcn_s_setprio(1);                                         \
      _Pragma("unroll") for (int h = 0; h < 2; ++h) {                        \
        const int row = c * 32 + h * 4 + rA;                                 \
        _Pragma("unroll") for (int kc = 0; kc < 2; ++kc) {                   \
          const f16x8 ka = *(const f16x8*)&Ks[nb][row * KSTR + kc * 32 + quad * 8]; \
          _Pragma("unroll") for (int nt = 0; nt < 4; ++nt)                   \
            scv[h][nt] = __builtin_amdgcn_mfma_f32_16x16x32_f16(             \
                ka, qf[nt][kc], scv[h][nt], 0, 0, 0);                        \
        }                                                                    \
      }                                                                      \
      __builtin_amdgcn_s_setprio(0);                                         \
      f16x8 pa[4];                                                           \
      _Pragma("unroll") for (int nt = 0; nt < 4; ++nt)                       \
        _Pragma("unroll") for (int h = 0; h < 2; ++h)                        \
          _Pragma("unroll") for (int r = 0; r < 4; ++r) {                    \
            const float e = __expf(scv[h][nt][r]);                           \
            rsum[nt] += e;                                                   \
            pa[nt][h * 4 + r] = (f16_t)e;                                    \
          }                                                                  \
      __builtin_amdgcn_s_setprio(1);                                         \
      _Pragma("unroll") for (int nd = 0; nd < 4; ++nd) {                     \
        const f16x8 vb = *(const f16x8*)&Vs[nb][(nd * 16 + l16) * KSTR + c * 32 + quad * 8]; \
        _Pragma("unroll") for (int nt = 0; nt < 4; ++nt)                     \
          oacc[nt][nd] = __builtin_amdgcn_mfma_f32_16x16x32_f16(             \
              pa[nt], vb, oacc[nt][nd], 0, 0, 0);                            \
      }                                                                      \
      __builtin_amdgcn_s_setprio(0);                                         \
    }                                                                        \
  } while (0)

  // Prologue: tile 0 staged (write latency exposed once), tile 1 in flight.
  LOADKV(0);
  WRITEKV(0);
  LOADKV(1);
  ATTN_SYNC;

  // Steady state: kt = 0..13 in even/odd pairs (compile-time buffer index).
  for (int kt = 0; kt < 14; kt += 2) {
    ATTN_COMPUTE(0);
    WRITEKV(1);          // regs = tile kt+1 (issued one compute ago)
    LOADKV(kt + 2);
    ATTN_SYNC;
    ATTN_COMPUTE(1);
    WRITEKV(0);          // regs = tile kt+2
    LOADKV(kt + 3);
    ATTN_SYNC;
  }
  // kt = 14: compute buf0, stage tile 15 (regs already loaded), no new loads.
  ATTN_COMPUTE(0);
  WRITEKV(1);
  ATTN_SYNC;
  // kt = 15
  ATTN_COMPUTE(1);

#undef LOADKV
#undef WRITEKV
#undef ATTN_SYNC
#undef ATTN_COMPUTE

  // Denominators: keys partitioned across quads -> reduce over quads.
#pragma unroll
  for (int nt = 0; nt < 4; ++nt) {
    float rs = rsum[nt];
    rs += __shfl_xor(rs, 16); rs += __shfl_xor(rs, 32);
    if (quad == 0) Ls[w][nt * 16 + l16] = rs;
  }
  asm volatile("s_waitcnt lgkmcnt(0)" ::: "memory");  // wave-private RAW

  // Epilogue: ao16[l, b, h*64+d] = oacc / denom (f16, feeds out-proj GEMM).
  const int b = bh >> 4;
  const int h = bh & 15;
#pragma unroll
  for (int nt = 0; nt < 4; ++nt)
#pragma unroll
    for (int r = 0; r < 4; ++r) {
      const int ql = nt * 16 + quad * 4 + r;
      const float inv = 1.0f / Ls[w][ql];
      const int qrow = q0 + ql;
#pragma unroll
      for (int nd = 0; nd < 4; ++nd) {
        const int d = nd * 16 + l16;
        O[((size_t)qrow * B_DIM + b) * E_DIM + h * HD + d] = (f16_t)(oacc[nt][nd][r] * inv);
      }
    }
}

extern "C" void kernel_launch(void* const* d_in, const int* in_sizes, int n_in,
                              void* d_out, int out_size, void* d_ws, size_t ws_size,
                              hipStream_t stream) {
  const float* x     = (const float*)d_in[0];
  const float* w_in  = (const float*)d_in[1];
  const float* b_in  = (const float*)d_in[2];
  const float* w_out = (const float*)d_in[3];
  const float* b_out = (const float*)d_in[4];

  const size_t TS = (size_t)BH_DIM * L_DIM * HD;  // 8M elements per tensor
  f16_t* q16  = (f16_t*)d_ws;
  f16_t* k16  = q16 + TS;
  f16_t* v16  = k16 + TS;
  f16_t* x16  = v16 + TS;
  f16_t* wi16 = x16 + TS;
  f16_t* wo16 = wi16 + (size_t)3 * E_DIM * E_DIM;
  f16_t* ao16 = x16;   // alias: x16 dead after QKV GEMM

  // 0) fp32 -> f16 pre-convert (x, w_in, w_out)
  convert_f16<<<4096, 256, 0, stream>>>(x, w_in, w_out, x16, wi16, wo16);
  // 1) QKV projection: 128^2 dbuf BK=64, 2 blocks/CU, grid 1536 (3x512 exact)
  gemm_qkv<<<1536, 256, 0, stream>>>(x16, wi16, b_in, q16, k16, v16);
  // 2) attention v6: dbuf K/V + async-stage split, 1 barrier/kt
  attn_f16<<<dim3(4, 128), 256, 0, stream>>>(q16, k16, v16, ao16);
  // 3) out projection: round-5 template, grid 512 = 2/CU exact
  gemm_out<<<512, 256, 0, stream>>>(ao16, wo16, b_out, (float*)d_out);
}

// Round 10
// 224.021 us; speedup vs baseline: 1.0131x; 1.0053x over previous
//
#include <hip/hip_runtime.h>

// Problem constants: x [L,B,E], H heads, head dim 64.
#define L_DIM 1024
#define B_DIM 8
#define E_DIM 1024
#define H_DIM 16
#define HD 64
#define BH_DIM (B_DIM * H_DIM)  // 128

typedef float f32x4 __attribute__((ext_vector_type(4)));
typedef _Float16 f16_t;
typedef f16_t f16x4 __attribute__((ext_vector_type(4)));
typedef f16_t f16x8 __attribute__((ext_vector_type(8)));

// async global->LDS, 16 B per lane (m97 pattern): wave-uniform base + lane*16.
static __device__ __forceinline__ void gld16(const void* g, void* l) {
  __builtin_amdgcn_global_load_lds(
      (const __attribute__((address_space(1))) unsigned int*)g,
      (__attribute__((address_space(3))) unsigned int*)l, 16, 0, 0);
}

// fp32 -> f16 pre-convert of x, w_in, w_out (grid-stride over float4 units).
__global__ __launch_bounds__(256) void convert_f16(
    const float* __restrict__ x, const float* __restrict__ wi,
    const float* __restrict__ wo, f16_t* __restrict__ x16,
    f16_t* __restrict__ wi16, f16_t* __restrict__ wo16) {
  const int NX = (L_DIM * B_DIM * E_DIM) / 4;   // 2097152
  const int NWI = (3 * E_DIM * E_DIM) / 4;      // 786432
  const int NWO = (E_DIM * E_DIM) / 4;          // 262144
  const int total = NX + NWI + NWO;
  for (int i = blockIdx.x * blockDim.x + threadIdx.x; i < total;
       i += gridDim.x * blockDim.x) {
    const float4* src; f16_t* dst; int j;
    if (i < NX)            { src = (const float4*)x;  dst = x16;  j = i; }
    else if (i < NX + NWI) { src = (const float4*)wi; dst = wi16; j = i - NX; }
    else                   { src = (const float4*)wo; dst = wo16; j = i - NX - NWI; }
    const float4 v = src[j];
    f16x4 h = {(f16_t)v.x, (f16_t)v.y, (f16_t)v.z, (f16_t)v.w};
    *(f16x4*)(dst + (size_t)j * 4) = h;
  }
}

#define GQ_FENCE asm volatile("" ::: "memory")
#define GQ_BARRIER do { GQ_FENCE; __builtin_amdgcn_s_barrier(); GQ_FENCE; } while (0)
#define VMW(n) asm volatile("s_waitcnt vmcnt(" #n ")" ::: "memory")
#define GQ_LGKM0 do { asm volatile("s_waitcnt lgkmcnt(0)" ::: "memory"); \
                      __builtin_amdgcn_sched_barrier(0); } while (0)

// swizzled frag pointer: logical byte = r*128 + ks*64 + quad*16, physical
// XORs (r&7)<<4.  r always = base + l16 so r&7 == l16&7.  Row stride 128 B
// (64 f16) in both QKV variants.  Measured 0 bank conflicts.
static __device__ __forceinline__ const f16x8* fp16frag(
    const f16_t* tile, int r, int ks, int quad, int l16) {
  const int bo = (r * 128 + ks * 64 + quad * 16) ^ ((l16 & 7) << 4);
  return (const f16x8*)((const char*)tile + bo);
}

// ---------------------------------------------------------------------------
// QKV variant A (within-session A/B arm 1): 256x256 8-phase schedule —
// round-1's kernel (passed correctness), regridded to N columns 0..2047
// (q and k chunks).  32 tm x 8 tn = 256 blocks = EXACTLY 1/CU, 512 thr.
// Rounds 1-4 only ever ran this under unknown clock state with a 1.5-round
// grid; this is its first clean-grid same-session test vs the 128² template.
// ---------------------------------------------------------------------------

#define STAGE_A2(d, ht, kt) do {                                             \
    gld16(Asrc + (size_t)(ht) * (128 * 1024) + (kt) * 64,                    \
          &As[(d) * 16384 + (ht) * 8192 + tid * 8]);                         \
    gld16(Asrc + (size_t)(ht) * (128 * 1024) + 64 * 1024 + (kt) * 64,        \
          &As[(d) * 16384 + (ht) * 8192 + 4096 + tid * 8]);                  \
  } while (0)
#define STAGE_B2(d, ht, kt) do {                                             \
    gld16(Bsrc + (size_t)(ht) * (128 * 1024) + (kt) * 64,                    \
          &Bs[(d) * 16384 + (ht) * 8192 + tid * 8]);                         \
    gld16(Bsrc + (size_t)(ht) * (128 * 1024) + 64 * 1024 + (kt) * 64,        \
          &Bs[(d) * 16384 + (ht) * 8192 + 4096 + tid * 8]);                  \
  } while (0)

#define PHA(d, g, STAGE_STMT, ENDWAIT) do {                                  \
    f16x8 af_[2][2];                                                         \
    _Pragma("unroll") for (int f_ = 0; f_ < 2; ++f_)                         \
      _Pragma("unroll") for (int ks_ = 0; ks_ < 2; ++ks_)                    \
        af_[f_][ks_] = *fp16frag(&As[(d) * 16384],                           \
            wr * 128 + ((g) * 2 + f_) * 16 + l16, ks_, quad, l16);           \
    if ((g) == 0) {                                                          \
      _Pragma("unroll") for (int c_ = 0; c_ < 4; ++c_)                       \
        _Pragma("unroll") for (int ks_ = 0; ks_ < 2; ++ks_)                  \
          bf[c_][ks_] = *fp16frag(&Bs[(d) * 16384],                          \
              wc * 64 + c_ * 16 + l16, ks_, quad, l16);                      \
    }                                                                        \
    STAGE_STMT;                                                              \
    GQ_BARRIER;                                                              \
    GQ_LGKM0;                                                                \
    __builtin_amdgcn_s_setprio(1);                                           \
    _Pragma("unroll") for (int f_ = 0; f_ < 2; ++f_)                         \
      _Pragma("unroll") for (int c_ = 0; c_ < 4; ++c_)                       \
        _Pragma("unroll") for (int ks_ = 0; ks_ < 2; ++ks_)                  \
          acc[(g) * 2 + f_][c_] = __builtin_amdgcn_mfma_f32_16x16x32_f16(    \
              af_[f_][ks_], bf[c_][ks_], acc[(g) * 2 + f_][c_], 0, 0, 0);    \
    __builtin_amdgcn_s_setprio(0);                                           \
    ENDWAIT;                                                                 \
    GQ_BARRIER;                                                              \
  } while (0)

__global__ __launch_bounds__(512, 2) void gemm_qkv_a(
    const f16_t* __restrict__ A, const f16_t* __restrict__ B,
    const float* __restrict__ bias, f16_t* __restrict__ Oq,
    f16_t* __restrict__ Ok, f16_t* __restrict__ Ov) {
  constexpr int K = 1024;
  constexpr int NT = K / 64;  // 16 K-tiles
  __shared__ __align__(16) f16_t As[2 * 16384];  // 64 KB: dbuf x 256x64
  __shared__ __align__(16) f16_t Bs[2 * 16384];  // 64 KB

  const int tid = threadIdx.x;
  const int lane = tid & 63;
  const int w = tid >> 6;       // 0..7
  const int wr = w >> 2;        // M half
  const int wc = w & 3;         // N quarter
  const int quad = lane >> 4;
  const int l16 = lane & 15;

  // XCD swizzle: 256 wg = 8 XCDs x 32; per XCD tm in [4x,4x+4) (A slab 2 MB
  // L2-resident), tn sweeps 0..7.
  const int bid = blockIdx.x;
  const int xcd = bid & 7;
  const int idx = bid >> 3;            // 0..31
  const int tm = xcd * 4 + (idx & 3);  // 0..31
  const int tn = idx >> 2;             // 0..7
  const int m0 = tm * 256;
  const int n0 = tn * 256;             // covers N 0..2047

  const int srow = tid >> 3;                      // 0..63
  const int scol = ((tid & 7) ^ (srow & 7)) * 8;  // pre-swizzled global col
  const f16_t* Asrc = A + (size_t)(m0 + srow) * K + scol;
  const f16_t* Bsrc = B + (size_t)(n0 + srow) * K + scol;

  f32x4 acc[8][4] = {};
  f16x8 bf[4][2];

  // Prologue: A(0), B(0), B(1); vmcnt(4) -> A(0)+B(0) done, B(1) in flight.
  STAGE_A2(0, 0, 0); STAGE_A2(0, 1, 0);
  STAGE_B2(0, 0, 0); STAGE_B2(0, 1, 0);
  STAGE_B2(1, 0, 1); STAGE_B2(1, 1, 1);
  VMW(4);
  GQ_BARRIER;

  for (int it = 0; it < 8; ++it) {
    const int t1 = 2 * it + 1;
    const int ta = (2 * it + 2 < NT) ? 2 * it + 2 : NT - 1;  // clamped tail
    const int tb = (2 * it + 3 < NT) ? 2 * it + 3 : NT - 1;
    PHA(0, 0, STAGE_A2(1, 0, t1), );
    PHA(0, 1, STAGE_A2(1, 1, t1), );
    PHA(0, 2, STAGE_B2(0, 0, ta), );
    PHA(0, 3, STAGE_B2(0, 1, ta), VMW(4));
    PHA(1, 0, STAGE_A2(0, 0, ta), );
    PHA(1, 1, STAGE_A2(0, 1, ta), );
    PHA(1, 2, STAGE_B2(1, 0, tb), );
    PHA(1, 3, STAGE_B2(1, 1, tb), VMW(4));
  }

  // Epilogue: C/D layout col=l16, row=quad*4+r.  n < 2048 -> chunks 0/1 only.
#pragma unroll
  for (int i = 0; i < 8; ++i) {
    const int mbase = m0 + wr * 128 + i * 16 + quad * 4;
#pragma unroll
    for (int c = 0; c < 4; ++c) {
      const int n = n0 + wc * 64 + c * 16 + l16;
      const float bv = bias[n];
      const int chunk = n >> 10;      // 0=q 1=k (uniform per 16-wide frag)
      const int e = n & 1023;
      const int h = e >> 6;
      const int d = e & 63;
#pragma unroll
      for (int r = 0; r < 4; ++r) {
        const int m = mbase + r;
        const int l = m >> 3, b = m & 7;          // row m = l*B + b
        const size_t idxo = ((size_t)(b * H_DIM + h) * L_DIM + l) * HD + d;
        const float val = acc[i][c][r] + bv;
        if (chunk == 0)      Oq[idxo] = (f16_t)(val * 0.125f);  // 64^-0.5
        else                 Ok[idxo] = (f16_t)val;
      }
    }
  }
}

// ---------------------------------------------------------------------------
// QKV variant B (A/B arm 2): the round-5 128x128 dbuf template, regridded to
// N columns 2048..3071 (v chunk).  64 tm x 8 tn = 512 blocks = EXACTLY 2/CU.
// ---------------------------------------------------------------------------
__global__ __launch_bounds__(256, 2) void gemm_qkv_b(
    const f16_t* __restrict__ A, const f16_t* __restrict__ B,
    const float* __restrict__ bias, f16_t* __restrict__ Ov) {
  constexpr int K = 1024;
  __shared__ __align__(16) f16_t As[2 * 8192];  // 32 KB: dbuf x 128x64
  __shared__ __align__(16) f16_t Bs[2 * 8192];  // 32 KB

  const int tid = threadIdx.x;
  const int lane = tid & 63;
  const int w = tid >> 6;        // 0..3
  const int wm = (w & 1) * 64;
  const int wn = (w >> 1) * 64;
  const int quad = lane >> 4;
  const int l16 = lane & 15;

  // XCD swizzle: 512 wg = 8 XCDs x 64; per XCD tm in [8x,8x+8), tn 0..7.
  const int bid = blockIdx.x;
  const int xcd = bid & 7;
  const int idx = bid >> 3;            // 0..63
  const int tm = xcd * 8 + (idx & 7);  // 0..63
  const int tn = idx >> 3;             // 0..7
  const int m0 = tm * 128;
  const int n0 = 2048 + tn * 128;      // covers N 2048..3071 (v)

  const int r8 = tid >> 3;                    // 0..31
  const int gsw = (tid & 7) ^ (r8 & 7);
  const f16_t* Abase = A + (size_t)(m0 + r8) * K + gsw * 8;
  const f16_t* Bbase = B + (size_t)(n0 + r8) * K + gsw * 8;

#define STAGE(kt, d) do {                                                    \
    _Pragma("unroll") for (int s_ = 0; s_ < 4; ++s_)                         \
      gld16(Abase + (size_t)s_ * 32 * K + (kt) * 64,                         \
            &As[(d) * 8192 + s_ * 2048 + tid * 8]);                          \
    _Pragma("unroll") for (int s_ = 0; s_ < 4; ++s_)                         \
      gld16(Bbase + (size_t)s_ * 32 * K + (kt) * 64,                         \
            &Bs[(d) * 8192 + s_ * 2048 + tid * 8]);                          \
  } while (0)

  f32x4 acc[4][4] = {};

  STAGE(0, 0);
  STAGE(1, 1);

#pragma unroll
  for (int t = 0; t < 16; ++t) {
    const int d = t & 1;
    VMW(8);
    GQ_BARRIER;

    f16x8 af[4][2], bf[4][2];
#pragma unroll
    for (int i = 0; i < 4; ++i)
#pragma unroll
      for (int ks = 0; ks < 2; ++ks) {
        af[i][ks] = *fp16frag(&As[d * 8192], wm + i * 16 + l16, ks, quad, l16);
        bf[i][ks] = *fp16frag(&Bs[d * 8192], wn + i * 16 + l16, ks, quad, l16);
      }

    __builtin_amdgcn_s_setprio(1);
#pragma unroll
    for (int i = 0; i < 4; ++i)
#pragma unroll
      for (int j = 0; j < 4; ++j)
#pragma unroll
        for (int ks = 0; ks < 2; ++ks)
          acc[i][j] = __builtin_amdgcn_mfma_f32_16x16x32_f16(
              af[i][ks], bf[j][ks], acc[i][j], 0, 0, 0);
    __builtin_amdgcn_s_setprio(0);

    GQ_BARRIER;
    const int kt2 = (t + 2 < 16) ? t + 2 : 15;
    STAGE(kt2, d);
  }

  // Epilogue: all columns are chunk 2 (v).
#pragma unroll
  for (int i = 0; i < 4; ++i) {
    const int mbase = m0 + wm + i * 16 + quad * 4;
#pragma unroll
    for (int c = 0; c < 4; ++c) {
      const int n = n0 + wn + c * 16 + l16;
      const float bv = bias[n];
      const int e = n & 1023;
      const int h = e >> 6;
      const int dd = e & 63;
#pragma unroll
      for (int r = 0; r < 4; ++r) {
        const int m = mbase + r;
        const int l = m >> 3, b = m & 7;          // row m = l*B + b
        const size_t idxo = ((size_t)(b * H_DIM + h) * L_DIM + l) * HD + dd;
        Ov[idxo] = (f16_t)(acc[i][c][r] + bv);
      }
    }
  }
#undef STAGE
}

// ---------------------------------------------------------------------------
// Out-proj GEMM (round-7 template, UNCHANGED).  Grid 512 = 2/CU exact.
// ---------------------------------------------------------------------------
__global__ __launch_bounds__(256, 2) void gemm_out(
    const f16_t* __restrict__ A, const f16_t* __restrict__ B,
    const float* __restrict__ bias, float* __restrict__ O) {
  constexpr int K = 1024;
  __shared__ __align__(16) f16_t As[2 * 8192];  // 32 KB
  __shared__ __align__(16) f16_t Bs[2 * 8192];  // 32 KB

  const int tid = threadIdx.x;
  const int lane = tid & 63;
  const int w = tid >> 6;        // 0..3
  const int wm = (w & 1) * 64;
  const int wn = (w >> 1) * 64;
  const int quad = lane >> 4;
  const int l16 = lane & 15;

  const int bid = blockIdx.x;
  const int xcd = bid & 7;
  const int idx = bid >> 3;            // 0..63
  const int tm = xcd * 8 + (idx & 7);  // 0..63
  const int tn = idx >> 3;             // 0..7
  const int m0 = tm * 128;
  const int n0 = tn * 128;

  const int r8 = tid >> 3;                    // 0..31
  const int gsw = (tid & 7) ^ (r8 & 7);
  const f16_t* Abase = A + (size_t)(m0 + r8) * K + gsw * 8;
  const f16_t* Bbase = B + (size_t)(n0 + r8) * K + gsw * 8;

#define STAGE(kt, d) do {                                                    \
    _Pragma("unroll") for (int s_ = 0; s_ < 4; ++s_)                         \
      gld16(Abase + (size_t)s_ * 32 * K + (kt) * 64,                         \
            &As[(d) * 8192 + s_ * 2048 + tid * 8]);                          \
    _Pragma("unroll") for (int s_ = 0; s_ < 4; ++s_)                         \
      gld16(Bbase + (size_t)s_ * 32 * K + (kt) * 64,                         \
            &Bs[(d) * 8192 + s_ * 2048 + tid * 8]);                          \
  } while (0)

  f32x4 acc[4][4] = {};

  STAGE(0, 0);
  STAGE(1, 1);

#pragma unroll
  for (int t = 0; t < 16; ++t) {
    const int d = t & 1;
    VMW(8);
    GQ_BARRIER;

    f16x8 af[4][2], bf[4][2];
#pragma unroll
    for (int i = 0; i < 4; ++i)
#pragma unroll
      for (int ks = 0; ks < 2; ++ks) {
        af[i][ks] = *fp16frag(&As[d * 8192], wm + i * 16 + l16, ks, quad, l16);
        bf[i][ks] = *fp16frag(&Bs[d * 8192], wn + i * 16 + l16, ks, quad, l16);
      }

    __builtin_amdgcn_s_setprio(1);
#pragma unroll
    for (int i = 0; i < 4; ++i)
#pragma unroll
      for (int j = 0; j < 4; ++j)
#pragma unroll
        for (int ks = 0; ks < 2; ++ks)
          acc[i][j] = __builtin_amdgcn_mfma_f32_16x16x32_f16(
              af[i][ks], bf[j][ks], acc[i][j], 0, 0, 0);
    __builtin_amdgcn_s_setprio(0);

    GQ_BARRIER;
    const int kt2 = (t + 2 < 16) ? t + 2 : 15;
    STAGE(kt2, d);
  }

  // fp32 epilogue with bias; C/D layout col=l16, row=quad*4+r.
#pragma unroll
  for (int i = 0; i < 4; ++i) {
    const int mbase = m0 + wm + i * 16 + quad * 4;
#pragma unroll
    for (int c = 0; c < 4; ++c) {
      const int n = n0 + wn + c * 16 + l16;
      const float bv = bias[n];
#pragma unroll
      for (int r = 0; r < 4; ++r) {
        const int m = mbase + r;
        O[(size_t)m * E_DIM + n] = acc[i][c][r] + bv;
      }
    }
  }
#undef STAGE
}

// ---------------------------------------------------------------------------
// Attention v6 (UNCHANGED): dbuf K/V LDS + async-stage split (T14), one RAW
// barrier per kt, no vmcnt drain at barriers.
// ---------------------------------------------------------------------------
__global__ __launch_bounds__(256, 2) void attn_f16(
    const f16_t* __restrict__ Q, const f16_t* __restrict__ K,
    const f16_t* __restrict__ V, f16_t* __restrict__ O) {
  constexpr int KSTR = 70;  // odd-dword row stride: <=2-way banks on frag reads
  __shared__ __align__(16) f16_t Ks[2][64 * KSTR];   // [key][d]
  __shared__ __align__(16) f16_t Vs[2][64 * KSTR];   // [d][key]  (V^T)
  __shared__ float Ls[4][64];

  const int tid = threadIdx.x;
  const int lane = tid & 63;
  const int w = tid >> 6;
  const int quad = lane >> 4;
  const int l16 = lane & 15;
  const int bh = blockIdx.y;
  const int q0 = blockIdx.x * 256 + w * 64;

  const f16_t* Qb = Q + (size_t)bh * L_DIM * HD;
  const f16_t* Kb = K + (size_t)bh * L_DIM * HD;
  const f16_t* Vb = V + (size_t)bh * L_DIM * HD;  // [key][d]

  // Q as B-operand frags (n=q=l16, k=d=quad*8+j).
  f16x8 qf[4][2];
#pragma unroll
  for (int nt = 0; nt < 4; ++nt)
#pragma unroll
    for (int kc = 0; kc < 2; ++kc)
      qf[nt][kc] = *(const f16x8*)(Qb + (size_t)(q0 + nt * 16 + l16) * HD + kc * 32 + quad * 8);

  f32x4 oacc[4][4] = {};   // [q-tile][d-tile]
  float rsum[4] = {0.0f, 0.0f, 0.0f, 0.0f};

  const int sr = tid >> 3;        // K staging row 0..31
  const int sc8 = (tid & 7) * 8;  // K staging col
  const int va = tid & 31;        // V staging: d-pair index
  const int vg = tid >> 5;        // V staging: key-group 0..7
  const int rA = (l16 >> 2) * 8 + (l16 & 3);  // permuted A-row base

  // staging registers (one set, refilled after each write)
  f16x8 kreg[2];
  unsigned int vd[8];

#define LOADKV(kt) do {                                                      \
    _Pragma("unroll") for (int rr_ = 0; rr_ < 2; ++rr_)                      \
      kreg[rr_] = *(const f16x8*)(Kb +                                       \
          (size_t)((kt) * 64 + sr + rr_ * 32) * HD + sc8);                   \
    const f16_t* vp_ = Vb + (size_t)((kt) * 64 + vg * 8) * HD + 2 * va;      \
    _Pragma("unroll") for (int i_ = 0; i_ < 8; ++i_)                         \
      vd[i_] = *(const unsigned int*)(vp_ + (size_t)i_ * HD);                \
  } while (0)

#define WRITEKV(nb) do {                                                     \
    _Pragma("unroll") for (int rr_ = 0; rr_ < 2; ++rr_)                      \
      *(f16x8*)&Ks[nb][(sr + rr_ * 32) * KSTR + sc8] = kreg[rr_];            \
    union { unsigned int u[4]; f16x8 v; } lo_, hi_;                          \
    _Pragma("unroll") for (int i_ = 0; i_ < 4; ++i_) {                       \
      lo_.u[i_] = (vd[2 * i_] & 0xffffu) | (vd[2 * i_ + 1] << 16);           \
      hi_.u[i_] = (vd[2 * i_] >> 16) | (vd[2 * i_ + 1] & 0xffff0000u);       \
    }                                                                        \
    *(f16x8*)&Vs[nb][(2 * va) * KSTR + vg * 8] = lo_.v;                      \
    *(f16x8*)&Vs[nb][(2 * va + 1) * KSTR + vg * 8] = hi_.v;                  \
  } while (0)

#define ATTN_SYNC do {                                                       \
    GQ_FENCE;                                                                \
    asm volatile("s_waitcnt lgkmcnt(0)" ::: "memory");                       \
    __builtin_amdgcn_s_barrier();                                            \
    GQ_FENCE;                                                                \
  } while (0)

#define ATTN_COMPUTE(nb) do {                                                \
    _Pragma("unroll") for (int c = 0; c < 2; ++c) {                          \
      f32x4 scv[2][4] = {};                                                  \
      __builtin_amdgcn_s_setprio(1);                                         \
      _Pragma("unroll") for (int h = 0; h < 2; ++h) {                        \
        const int row = c * 32 + h * 4 + rA;                                 \
        _Pragma("unroll") for (int kc = 0; kc < 2; ++kc) {                   \
          const f16x8 ka = *(const f16x8*)&Ks[nb][row * KSTR + kc * 32 + quad * 8]; \
          _Pragma("unroll") for (int nt = 0; nt < 4; ++nt)                   \
            scv[h][nt] = __builtin_amdgcn_mfma_f32_16x16x32_f16(             \
                ka, qf[nt][kc], scv[h][nt], 0, 0, 0);                        \
        }                                                                    \
      }                                                                      \
      __builtin_amdgcn_s_setprio(0);                                         \
      f16x8 pa[4];                                                           \
      _Pragma("unroll") for (int nt = 0; nt < 4; ++nt)                       \
        _Pragma("unroll") for (int h = 0; h < 2; ++h)                        \
          _Pragma("unroll") for (int r = 0; r < 4; ++r) {                    \
            const float e = __expf(scv[h][nt][r]);                           \
            rsum[nt] += e;                                                   \
            pa[nt][h * 4 + r] = (f16_t)e;                                    \
          }                                                                  \
      __builtin_amdgcn_s_setprio(1);                                         \
      _Pragma("unroll") for (int nd = 0; nd < 4; ++nd) {                     \
        const f16x8 vb = *(const f16x8*)&Vs[nb][(nd * 16 + l16) * KSTR + c * 32 + quad * 8]; \
        _Pragma("unroll") for (int nt = 0; nt < 4; ++nt)                     \
          oacc[nt][nd] = __builtin_amdgcn_mfma_f32_16x16x32_f16(             \
              pa[nt], vb, oacc[nt][nd], 0, 0, 0);                            \
      }                                                                      \
      __builtin_amdgcn_s_setprio(0);                                         \
    }                                                                        \
  } while (0)

  // Prologue: tile 0 staged (write latency exposed once), tile 1 in flight.
  LOADKV(0);
  WRITEKV(0);
  LOADKV(1);
  ATTN_SYNC;

  // Steady state: kt = 0..13 in even/odd pairs (compile-time buffer index).
  for (int kt = 0; kt < 14; kt += 2) {
    ATTN_COMPUTE(0);
    WRITEKV(1);          // regs = tile kt+1 (issued one compute ago)
    LOADKV(kt + 2);
    ATTN_SYNC;
    ATTN_COMPUTE(1);
    WRITEKV(0);          // regs = tile kt+2
    LOADKV(kt + 3);
    ATTN_SYNC;
  }
  // kt = 14: compute buf0, stage tile 15 (regs already loaded), no new loads.
  ATTN_COMPUTE(0);
  WRITEKV(1);
  ATTN_SYNC;
  // kt = 15
  ATTN_COMPUTE(1);

#undef LOADKV
#undef WRITEKV
#undef ATTN_SYNC
#undef ATTN_COMPUTE

  // Denominators: keys partitioned across quads -> reduce over quads.
#pragma unroll
  for (int nt = 0; nt < 4; ++nt) {
    float rs = rsum[nt];
    rs += __shfl_xor(rs, 16); rs += __shfl_xor(rs, 32);
    if (quad == 0) Ls[w][nt * 16 + l16] = rs;
  }
  asm volatile("s_waitcnt lgkmcnt(0)" ::: "memory");  // wave-private RAW

  // Epilogue: ao16[l, b, h*64+d] = oacc / denom (f16, feeds out-proj GEMM).
  const int b = bh >> 4;
  const int h = bh & 15;
#pragma unroll
  for (int nt = 0; nt < 4; ++nt)
#pragma unroll
    for (int r = 0; r < 4; ++r) {
      const int ql = nt * 16 + quad * 4 + r;
      const float inv = 1.0f / Ls[w][ql];
      const int qrow = q0 + ql;
#pragma unroll
      for (int nd = 0; nd < 4; ++nd) {
        const int d = nd * 16 + l16;
        O[((size_t)qrow * B_DIM + b) * E_DIM + h * HD + d] = (f16_t)(oacc[nt][nd][r] * inv);
      }
    }
}

extern "C" void kernel_launch(void* const* d_in, const int* in_sizes, int n_in,
                              void* d_out, int out_size, void* d_ws, size_t ws_size,
                              hipStream_t stream) {
  const float* x     = (const float*)d_in[0];
  const float* w_in  = (const float*)d_in[1];
  const float* b_in  = (const float*)d_in[2];
  const float* w_out = (const float*)d_in[3];
  const float* b_out = (const float*)d_in[4];

  const size_t TS = (size_t)BH_DIM * L_DIM * HD;  // 8M elements per tensor
  f16_t* q16  = (f16_t*)d_ws;
  f16_t* k16  = q16 + TS;
  f16_t* v16  = k16 + TS;
  f16_t* x16  = v16 + TS;
  f16_t* wi16 = x16 + TS;
  f16_t* wo16 = wi16 + (size_t)3 * E_DIM * E_DIM;
  f16_t* ao16 = x16;   // alias: x16 dead after QKV GEMM

  // 0) fp32 -> f16 pre-convert (x, w_in, w_out)
  convert_f16<<<4096, 256, 0, stream>>>(x, w_in, w_out, x16, wi16, wo16);
  // 1a) QKV cols 0..2047 (q,k): 256^2 8-phase, 256 wg = 1/CU exact
  gemm_qkv_a<<<256, 512, 0, stream>>>(x16, wi16, b_in, q16, k16, v16);
  // 1b) QKV cols 2048..3071 (v): 128^2 dbuf, 512 wg = 2/CU exact
  gemm_qkv_b<<<512, 256, 0, stream>>>(x16, wi16, b_in, v16);
  // 2) attention v6
  attn_f16<<<dim3(4, 128), 256, 0, stream>>>(q16, k16, v16, ao16);
  // 3) out projection
  gemm_out<<<512, 256, 0, stream>>>(ao16, wo16, b_out, (float*)d_out);
}